// Round 6
// baseline (224.004 us; speedup 1.0000x reference)
//
#include <hip/hip_runtime.h>
#include <hip/hip_bf16.h>

typedef _Float16 f16;
typedef _Float16 f16x8 __attribute__((ext_vector_type(8)));
typedef float f32x4 __attribute__((ext_vector_type(4)));

#define NB 8
#define NT 2048
#define NE 1024
#define NH 64

#define CHUNKS_PER_BATCH 144   // sum over qi=0..31 of ceil((qi+1)/4)
#define MAXC 8                 // max chunks per q-row

// ws layout (bytes)
#define OFF_WT 0
#define OFF_QH 393216
#define OFF_KH 2490368
#define OFF_VT 4587520
#define OFF_ML 6684672          // 16384*8 float2  = 1 MiB
#define OFF_OP 7733248          // 16384*8*64 f16  = 16 MiB

// ---------------- kernel 0: weight convert + transpose (coalesced) -------
// grid = 3 mats x 16 e-tiles of 64; LDS transpose, both sides coalesced
__global__ __launch_bounds__(256) void wconv_kernel(
        const float* __restrict__ Wk, const float* __restrict__ Wq,
        const float* __restrict__ Wv, f16* __restrict__ wt) {
    __shared__ float tile[64][65];
    const int mat = blockIdx.x >> 4;
    const int e0 = (blockIdx.x & 15) * 64;
    const float* W = (mat == 0) ? Wq : (mat == 1) ? Wk : Wv;
    const int tx = threadIdx.x & 63;
    const int ty = threadIdx.x >> 6;
#pragma unroll
    for (int r = ty; r < 64; r += 4)
        tile[r][tx] = W[(size_t)(e0 + r) * NH + tx];   // 256B coalesced read
    __syncthreads();
#pragma unroll
    for (int h = ty; h < 64; h += 4)
        wt[(size_t)mat * (NH * NE) + (size_t)h * NE + e0 + tx] = (f16)tile[tx][h];  // 128B coalesced write
}

// ---------------- kernel 1: fused QKV projection (MFMA f16) --------------
// x [16384][1024] fp32, wt [3][64][1024] f16 -> Qh,Kh [B*T][64], VT [B][64][T]
// block: 4 waves share 16 x-rows, N-split 4x3-tiles; grid 1024 -> 4 waves/SIMD
__global__ __launch_bounds__(256) void qkv_proj_kernel(
        const float* __restrict__ x, const f16* __restrict__ wt,
        f16* __restrict__ Qh, f16* __restrict__ Kh, f16* __restrict__ VT) {
    const int wave = threadIdx.x >> 6;
    const int lane = threadIdx.x & 63;
    const int lr = lane & 15;
    const int lg = lane >> 4;
    const int m0 = blockIdx.x * 16;     // 16 rows per block (shared by all waves)
    const int nt0 = wave * 3;           // this wave's 3 N-tiles of 12

    f32x4 acc[3] = {};

#pragma unroll 2
    for (int kk = 0; kk < NE; kk += 32) {
        const float* px = x + (size_t)(m0 + lr) * NE + kk + lg * 8;
        float4 u0 = *(const float4*)px;
        float4 u1 = *(const float4*)(px + 4);
        f16x8 a = { (f16)u0.x, (f16)u0.y, (f16)u0.z, (f16)u0.w,
                    (f16)u1.x, (f16)u1.y, (f16)u1.z, (f16)u1.w };
#pragma unroll
        for (int j = 0; j < 3; ++j) {
            int nt = nt0 + j;
            const f16* pw = wt + (size_t)(nt >> 2) * (NH * NE)
                               + (size_t)((nt & 3) * 16 + lr) * NE + kk + lg * 8;
            f16x8 b = *(const f16x8*)pw;
            acc[j] = __builtin_amdgcn_mfma_f32_16x16x32_f16(a, b, acc[j], 0, 0, 0);
        }
    }

#pragma unroll
    for (int j = 0; j < 3; ++j) {
        int nt = nt0 + j;
        int mat = nt >> 2;
        int ncol = (nt & 3) * 16 + lr;
#pragma unroll
        for (int r = 0; r < 4; ++r) {
            int m = m0 + lg * 4 + r;
            f16 val = (f16)acc[j][r];
            if (mat == 0) {
                Qh[(size_t)m * NH + ncol] = val;
            } else if (mat == 1) {
                Kh[(size_t)m * NH + ncol] = val;
            } else {
                int bb = m >> 11;
                int tt = m & 2047;
                VT[((size_t)bb * NH + ncol) * NT + tt] = val;
            }
        }
    }
}

// ---------------- kernel 2: causal flash attention, split-KV partials ----
// grid = NB * CHUNKS_PER_BATCH; each block: 64 q rows (4 waves x 16), <=8 KV steps
__global__ __launch_bounds__(256) void attn_part_kernel(
        const f16* __restrict__ Qh, const f16* __restrict__ Kh,
        const f16* __restrict__ VT, f16* __restrict__ op, float2* __restrict__ ml) {
    __shared__ f16 pbuf[4][16][40];

    const int wave = threadIdx.x >> 6;
    const int lane = threadIdx.x & 63;
    const int lr = lane & 15;
    const int lg = lane >> 4;

    const int b = blockIdx.x / CHUNKS_PER_BATCH;
    int c = blockIdx.x % CHUNKS_PER_BATCH;
    int qi = 0;
    for (; qi < 32; ++qi) {
        int ncq = (qi + 4) >> 2;
        if (c < ncq) break;
        c -= ncq;
    }
    const int total_steps = (qi + 1) * 2;       // 32-key steps in this q-block's range
    const int sbeg = c * 8;
    const int send = min(sbeg + 8, total_steps);
    const int qbase = qi * 64;
    const int qrow = qbase + wave * 16;

    const f16* Qb = Qh + (size_t)b * NT * NH;
    const f16* Kb = Kh + (size_t)b * NT * NH;
    const f16* Vb = VT + (size_t)b * NH * NT;

    f16x8 qf[2];
#pragma unroll
    for (int h = 0; h < 2; ++h)
        qf[h] = *(const f16x8*)(Qb + (size_t)(qrow + lr) * NH + h * 32 + lg * 8);

    f32x4 o[4] = {};
    float mrow[4], lrow[4];
#pragma unroll
    for (int r = 0; r < 4; ++r) { mrow[r] = -INFINITY; lrow[r] = 0.f; }

    const float scale = 0.125f;

    for (int s = sbeg; s < send; ++s) {
        const int s0 = s * 32;

        f32x4 S[2] = {};
#pragma unroll
        for (int t = 0; t < 2; ++t) {
#pragma unroll
            for (int h = 0; h < 2; ++h) {
                f16x8 kf = *(const f16x8*)(Kb + (size_t)(s0 + t * 16 + lr) * NH + h * 32 + lg * 8);
                S[t] = __builtin_amdgcn_mfma_f32_16x16x32_f16(qf[h], kf, S[t], 0, 0, 0);
            }
        }

#pragma unroll
        for (int t = 0; t < 2; ++t) {
#pragma unroll
            for (int r = 0; r < 4; ++r) {
                int q = qrow + lg * 4 + r;
                int key = s0 + t * 16 + lr;
                float sv = S[t][r] * scale;
                S[t][r] = (key <= q) ? sv : -INFINITY;
            }
        }

        float mx[4];
#pragma unroll
        for (int r = 0; r < 4; ++r) mx[r] = fmaxf(S[0][r], S[1][r]);
#pragma unroll
        for (int d = 1; d < 16; d <<= 1) {
#pragma unroll
            for (int r = 0; r < 4; ++r) mx[r] = fmaxf(mx[r], __shfl_xor(mx[r], d));
        }

        float f[4], nms[4];
#pragma unroll
        for (int r = 0; r < 4; ++r) {
            float nm = fmaxf(mrow[r], mx[r]);
            nms[r] = (nm == -INFINITY) ? 0.f : nm;   // NaN guard for fully-masked rows
            f[r] = __expf(mrow[r] - nms[r]);          // 0 when mrow == -inf
            mrow[r] = nm;
        }

#pragma unroll
        for (int t = 0; t < 2; ++t) {
#pragma unroll
            for (int r = 0; r < 4; ++r) S[t][r] = __expf(S[t][r] - nms[r]);
        }

#pragma unroll
        for (int r = 0; r < 4; ++r) {
            float rsum = S[0][r] + S[1][r];
#pragma unroll
            for (int d = 1; d < 16; d <<= 1) rsum += __shfl_xor(rsum, d);
            lrow[r] = lrow[r] * f[r] + rsum;
        }

#pragma unroll
        for (int ht = 0; ht < 4; ++ht) {
#pragma unroll
            for (int r = 0; r < 4; ++r) o[ht][r] *= f[r];
        }

        // per-wave LDS transpose (pbuf[wave] is wave-private; same-wave LDS ops ordered)
#pragma unroll
        for (int t = 0; t < 2; ++t) {
#pragma unroll
            for (int r = 0; r < 4; ++r)
                pbuf[wave][lg * 4 + r][t * 16 + lr] = (f16)S[t][r];
        }
        __builtin_amdgcn_wave_barrier();
        f16x8 pf = *(const f16x8*)(&pbuf[wave][lr][lg * 8]);

#pragma unroll
        for (int ht = 0; ht < 4; ++ht) {
            f16x8 vf = *(const f16x8*)(Vb + (size_t)(ht * 16 + lr) * NT + s0 + lg * 8);
            o[ht] = __builtin_amdgcn_mfma_f32_16x16x32_f16(pf, vf, o[ht], 0, 0, 0);
        }
        __builtin_amdgcn_wave_barrier();
    }

    // ---- write partials (unnormalized o, running m/l)
#pragma unroll
    for (int r = 0; r < 4; ++r) {
        int qt = qrow + lg * 4 + r;
        size_t slot = ((size_t)b * NT + qt) * MAXC + c;
#pragma unroll
        for (int ht = 0; ht < 4; ++ht)
            op[slot * NH + ht * 16 + lr] = (f16)o[ht][r];
        if (lr == 0) {
            float2 v; v.x = mrow[r]; v.y = lrow[r];
            ml[slot] = v;
        }
    }
}

// ---------------- kernel 3: combine split-KV partials --------------------
__global__ __launch_bounds__(256) void combine_kernel(
        const f16* __restrict__ op, const float2* __restrict__ ml,
        float* __restrict__ out) {
    int gid = blockIdx.x * 256 + threadIdx.x;
    int row = gid >> 6;        // b*2048 + q
    int h = gid & 63;
    int q = row & (NT - 1);
    int qi = q >> 6;
    int nc = (qi + 4) >> 2;

    size_t base = (size_t)row * MAXC;
    float2 ml0 = ml[base];
    float M = ml0.x, L = ml0.y;
    float O = (float)op[base * NH + h];
    for (int cc = 1; cc < nc; ++cc) {
        float2 mlc = ml[base + cc];
        if (mlc.x == -INFINITY) continue;      // chunk fully masked for this row
        float oc = (float)op[(base + cc) * NH + h];
        float nM = fmaxf(M, mlc.x);
        float wo = __expf(M - nM), wc = __expf(mlc.x - nM);
        O = O * wo + oc * wc;
        L = L * wo + mlc.y * wc;
        M = nM;
    }
    out[gid] = O / L;
}

extern "C" void kernel_launch(void* const* d_in, const int* in_sizes, int n_in,
                              void* d_out, int out_size, void* d_ws, size_t ws_size,
                              hipStream_t stream) {
    const float* x  = (const float*)d_in[0];
    const float* Wk = (const float*)d_in[1];
    const float* Wq = (const float*)d_in[2];
    const float* Wv = (const float*)d_in[3];
    float* out = (float*)d_out;

    char* ws = (char*)d_ws;
    f16* wt    = (f16*)(ws + OFF_WT);
    f16* Qh    = (f16*)(ws + OFF_QH);
    f16* Kh    = (f16*)(ws + OFF_KH);
    f16* VT    = (f16*)(ws + OFF_VT);
    float2* ml = (float2*)(ws + OFF_ML);
    f16* op    = (f16*)(ws + OFF_OP);

    hipLaunchKernelGGL(wconv_kernel, dim3(48), dim3(256), 0, stream, Wk, Wq, Wv, wt);
    hipLaunchKernelGGL(qkv_proj_kernel, dim3(1024), dim3(256), 0, stream, x, wt, Qh, Kh, VT);
    hipLaunchKernelGGL(attn_part_kernel, dim3(NB * CHUNKS_PER_BATCH), dim3(256), 0, stream,
                       Qh, Kh, VT, op, ml);
    hipLaunchKernelGGL(combine_kernel, dim3(NB * NT * NH / 256), dim3(256), 0, stream,
                       op, ml, out);
}

// Round 7
// 173.699 us; speedup vs baseline: 1.2896x; 1.2896x over previous
//
#include <hip/hip_runtime.h>
#include <hip/hip_bf16.h>

typedef _Float16 f16;
typedef _Float16 f16x8 __attribute__((ext_vector_type(8)));
typedef float f32x4 __attribute__((ext_vector_type(4)));

#define NB 8
#define NT 2048
#define NE 1024
#define NH 64

#define CHUNKS_PER_BATCH 144   // sum over qi=0..31 of ceil((qi+1)/4)
#define MAXC 8                 // max chunks per q-row

// ws layout (bytes)
#define OFF_WT 0
#define OFF_QH 393216
#define OFF_KH 2490368
#define OFF_VT 4587520
#define OFF_ML 6684672          // 16384*8 float2  = 1 MiB
#define OFF_OP 7733248          // 16384*8*64 f16  = 16 MiB

// ---------------- kernel 0: weight convert + transpose (coalesced) -------
__global__ __launch_bounds__(256) void wconv_kernel(
        const float* __restrict__ Wk, const float* __restrict__ Wq,
        const float* __restrict__ Wv, f16* __restrict__ wt) {
    __shared__ float tile[64][65];
    const int mat = blockIdx.x >> 4;
    const int e0 = (blockIdx.x & 15) * 64;
    const float* W = (mat == 0) ? Wq : (mat == 1) ? Wk : Wv;
    const int tx = threadIdx.x & 63;
    const int ty = threadIdx.x >> 6;
#pragma unroll
    for (int r = ty; r < 64; r += 4)
        tile[r][tx] = W[(size_t)(e0 + r) * NH + tx];
    __syncthreads();
#pragma unroll
    for (int h = ty; h < 64; h += 4)
        wt[(size_t)mat * (NH * NE) + (size_t)h * NE + e0 + tx] = (f16)tile[tx][h];
}

// ---------------- kernel 1: QKV projection, LDS-staged pipeline ----------
// x [16384][1024] fp32, wt [192][1024] f16 (q,k,v stacked)
// Tile: BM=64, BN=192(all), BK=64. 256 blocks x 4 waves.
// Wave owns 4 m-tiles x 3 n-tiles = 12 accs; per k-32: 7 ds_read_b128 + 12 MFMA.
// LDS rows are 128B; XOR-swizzle byte^=(row&7)<<4 on both write and read (T2).
// 1-chunk register prefetch: issue global loads early, ds_write after barrier (T14).
__global__ __launch_bounds__(256) void qkv_proj_kernel(
        const float* __restrict__ x, const f16* __restrict__ wt,
        f16* __restrict__ Qh, f16* __restrict__ Kh, f16* __restrict__ VT) {
    __shared__ f16 xs[2][64 * 64];     // 8 KB per buf
    __shared__ f16 wsb[2][192 * 64];   // 24 KB per buf

    const int tid = threadIdx.x;
    const int wave = tid >> 6;
    const int lane = tid & 63;
    const int lr = lane & 15;
    const int lg = lane >> 4;
    const int m0 = blockIdx.x * 64;
    const int nt0 = wave * 3;

    f32x4 acc[12] = {};   // [mt*3 + j]

    // staging registers (static-indexed -> stay in VGPRs)
    float4 xr0, xr1, xr2, xr3;
    int4 wr0, wr1, wr2, wr3, wr4, wr5;

    const int xrow = tid >> 2;          // 0..63
    const int xcg = (tid & 3) * 16;     // float col group (16 floats)

#define ISSUE_LOADS(kc)                                                        \
    do {                                                                       \
        const float* xb = x + (size_t)(m0 + xrow) * NE + (kc) + xcg;           \
        xr0 = *(const float4*)(xb);                                            \
        xr1 = *(const float4*)(xb + 4);                                        \
        xr2 = *(const float4*)(xb + 8);                                        \
        xr3 = *(const float4*)(xb + 12);                                       \
        wr0 = *(const int4*)(wt + (size_t)((tid + 0 * 256) >> 3) * NE + (kc) + ((tid + 0 * 256) & 7) * 8); \
        wr1 = *(const int4*)(wt + (size_t)((tid + 1 * 256) >> 3) * NE + (kc) + ((tid + 1 * 256) & 7) * 8); \
        wr2 = *(const int4*)(wt + (size_t)((tid + 2 * 256) >> 3) * NE + (kc) + ((tid + 2 * 256) & 7) * 8); \
        wr3 = *(const int4*)(wt + (size_t)((tid + 3 * 256) >> 3) * NE + (kc) + ((tid + 3 * 256) & 7) * 8); \
        wr4 = *(const int4*)(wt + (size_t)((tid + 4 * 256) >> 3) * NE + (kc) + ((tid + 4 * 256) & 7) * 8); \
        wr5 = *(const int4*)(wt + (size_t)((tid + 5 * 256) >> 3) * NE + (kc) + ((tid + 5 * 256) & 7) * 8); \
    } while (0)

#define CVT8(dst, a0, a1)                                                      \
    f16x8 dst = { (f16)a0.x, (f16)a0.y, (f16)a0.z, (f16)a0.w,                  \
                  (f16)a1.x, (f16)a1.y, (f16)a1.z, (f16)a1.w }

#define WRITE_LDS(buf)                                                         \
    do {                                                                       \
        { CVT8(v0, xr0, xr1);                                                  \
          int c = (tid & 3) * 2;                                               \
          int byo = xrow * 128 + ((c * 16) ^ ((xrow & 7) << 4));               \
          *(f16x8*)((char*)xs[buf] + byo) = v0; }                              \
        { CVT8(v1, xr2, xr3);                                                  \
          int c = (tid & 3) * 2 + 1;                                           \
          int byo = xrow * 128 + ((c * 16) ^ ((xrow & 7) << 4));               \
          *(f16x8*)((char*)xs[buf] + byo) = v1; }                              \
        { int jw = tid + 0 * 256, n = jw >> 3, c = jw & 7;                     \
          *(int4*)((char*)wsb[buf] + n * 128 + ((c * 16) ^ ((n & 7) << 4))) = wr0; } \
        { int jw = tid + 1 * 256, n = jw >> 3, c = jw & 7;                     \
          *(int4*)((char*)wsb[buf] + n * 128 + ((c * 16) ^ ((n & 7) << 4))) = wr1; } \
        { int jw = tid + 2 * 256, n = jw >> 3, c = jw & 7;                     \
          *(int4*)((char*)wsb[buf] + n * 128 + ((c * 16) ^ ((n & 7) << 4))) = wr2; } \
        { int jw = tid + 3 * 256, n = jw >> 3, c = jw & 7;                     \
          *(int4*)((char*)wsb[buf] + n * 128 + ((c * 16) ^ ((n & 7) << 4))) = wr3; } \
        { int jw = tid + 4 * 256, n = jw >> 3, c = jw & 7;                     \
          *(int4*)((char*)wsb[buf] + n * 128 + ((c * 16) ^ ((n & 7) << 4))) = wr4; } \
        { int jw = tid + 5 * 256, n = jw >> 3, c = jw & 7;                     \
          *(int4*)((char*)wsb[buf] + n * 128 + ((c * 16) ^ ((n & 7) << 4))) = wr5; } \
    } while (0)

    // prologue: stage chunk 0
    ISSUE_LOADS(0);
    WRITE_LDS(0);
    __syncthreads();

    int cur = 0;
    for (int c = 0; c < 16; ++c) {
        if (c < 15) ISSUE_LOADS((c + 1) * 64);

        // compute chunk c from buf cur
#pragma unroll
        for (int ks = 0; ks < 2; ++ks) {
            f16x8 af[4], bf[3];
#pragma unroll
            for (int mt = 0; mt < 4; ++mt) {
                int row = mt * 16 + lr;
                int byo = row * 128 + ((ks * 64 + lg * 16) ^ ((row & 7) << 4));
                af[mt] = *(const f16x8*)((const char*)xs[cur] + byo);
            }
#pragma unroll
            for (int j = 0; j < 3; ++j) {
                int n = (nt0 + j) * 16 + lr;
                int byo = n * 128 + ((ks * 64 + lg * 16) ^ ((n & 7) << 4));
                bf[j] = *(const f16x8*)((const char*)wsb[cur] + byo);
            }
#pragma unroll
            for (int mt = 0; mt < 4; ++mt)
#pragma unroll
                for (int j = 0; j < 3; ++j)
                    acc[mt * 3 + j] = __builtin_amdgcn_mfma_f32_16x16x32_f16(
                        af[mt], bf[j], acc[mt * 3 + j], 0, 0, 0);
        }

        __syncthreads();
        if (c < 15) {
            WRITE_LDS(cur ^ 1);
            __syncthreads();
        }
        cur ^= 1;
    }

    // epilogue: D layout row=(lane>>4)*4+r, col=lane&15
#pragma unroll
    for (int j = 0; j < 3; ++j) {
        int nbase = (nt0 + j) * 16;
        int mat = nbase >> 6;          // uniform per (wave, j)
        int ncol = (nbase & 63) + lr;
#pragma unroll
        for (int mt = 0; mt < 4; ++mt) {
#pragma unroll
            for (int r = 0; r < 4; ++r) {
                int m = m0 + mt * 16 + lg * 4 + r;
                f16 val = (f16)acc[mt * 3 + j][r];
                if (mat == 0) {
                    Qh[(size_t)m * NH + ncol] = val;
                } else if (mat == 1) {
                    Kh[(size_t)m * NH + ncol] = val;
                } else {
                    int bb = m >> 11;
                    int tt = m & 2047;
                    VT[((size_t)bb * NH + ncol) * NT + tt] = val;
                }
            }
        }
    }
#undef ISSUE_LOADS
#undef CVT8
#undef WRITE_LDS
}

// ---------------- kernel 2: causal flash attention, split-KV partials ----
__global__ __launch_bounds__(256) void attn_part_kernel(
        const f16* __restrict__ Qh, const f16* __restrict__ Kh,
        const f16* __restrict__ VT, f16* __restrict__ op, float2* __restrict__ ml) {
    __shared__ f16 pbuf[4][16][40];

    const int wave = threadIdx.x >> 6;
    const int lane = threadIdx.x & 63;
    const int lr = lane & 15;
    const int lg = lane >> 4;

    const int b = blockIdx.x / CHUNKS_PER_BATCH;
    int c = blockIdx.x % CHUNKS_PER_BATCH;
    int qi = 0;
    for (; qi < 32; ++qi) {
        int ncq = (qi + 4) >> 2;
        if (c < ncq) break;
        c -= ncq;
    }
    const int total_steps = (qi + 1) * 2;
    const int sbeg = c * 8;
    const int send = min(sbeg + 8, total_steps);
    const int qbase = qi * 64;
    const int qrow = qbase + wave * 16;

    const f16* Qb = Qh + (size_t)b * NT * NH;
    const f16* Kb = Kh + (size_t)b * NT * NH;
    const f16* Vb = VT + (size_t)b * NH * NT;

    f16x8 qf[2];
#pragma unroll
    for (int h = 0; h < 2; ++h)
        qf[h] = *(const f16x8*)(Qb + (size_t)(qrow + lr) * NH + h * 32 + lg * 8);

    f32x4 o[4] = {};
    float mrow[4], lrow[4];
#pragma unroll
    for (int r = 0; r < 4; ++r) { mrow[r] = -INFINITY; lrow[r] = 0.f; }

    const float scale = 0.125f;

    for (int s = sbeg; s < send; ++s) {
        const int s0 = s * 32;

        f32x4 S[2] = {};
#pragma unroll
        for (int t = 0; t < 2; ++t) {
#pragma unroll
            for (int h = 0; h < 2; ++h) {
                f16x8 kf = *(const f16x8*)(Kb + (size_t)(s0 + t * 16 + lr) * NH + h * 32 + lg * 8);
                S[t] = __builtin_amdgcn_mfma_f32_16x16x32_f16(qf[h], kf, S[t], 0, 0, 0);
            }
        }

#pragma unroll
        for (int t = 0; t < 2; ++t) {
#pragma unroll
            for (int r = 0; r < 4; ++r) {
                int q = qrow + lg * 4 + r;
                int key = s0 + t * 16 + lr;
                float sv = S[t][r] * scale;
                S[t][r] = (key <= q) ? sv : -INFINITY;
            }
        }

        float mx[4];
#pragma unroll
        for (int r = 0; r < 4; ++r) mx[r] = fmaxf(S[0][r], S[1][r]);
#pragma unroll
        for (int d = 1; d < 16; d <<= 1) {
#pragma unroll
            for (int r = 0; r < 4; ++r) mx[r] = fmaxf(mx[r], __shfl_xor(mx[r], d));
        }

        float f[4], nms[4];
#pragma unroll
        for (int r = 0; r < 4; ++r) {
            float nm = fmaxf(mrow[r], mx[r]);
            nms[r] = (nm == -INFINITY) ? 0.f : nm;
            f[r] = __expf(mrow[r] - nms[r]);
            mrow[r] = nm;
        }

#pragma unroll
        for (int t = 0; t < 2; ++t) {
#pragma unroll
            for (int r = 0; r < 4; ++r) S[t][r] = __expf(S[t][r] - nms[r]);
        }

#pragma unroll
        for (int r = 0; r < 4; ++r) {
            float rsum = S[0][r] + S[1][r];
#pragma unroll
            for (int d = 1; d < 16; d <<= 1) rsum += __shfl_xor(rsum, d);
            lrow[r] = lrow[r] * f[r] + rsum;
        }

#pragma unroll
        for (int ht = 0; ht < 4; ++ht) {
#pragma unroll
            for (int r = 0; r < 4; ++r) o[ht][r] *= f[r];
        }

#pragma unroll
        for (int t = 0; t < 2; ++t) {
#pragma unroll
            for (int r = 0; r < 4; ++r)
                pbuf[wave][lg * 4 + r][t * 16 + lr] = (f16)S[t][r];
        }
        __builtin_amdgcn_wave_barrier();
        f16x8 pf = *(const f16x8*)(&pbuf[wave][lr][lg * 8]);

#pragma unroll
        for (int ht = 0; ht < 4; ++ht) {
            f16x8 vf = *(const f16x8*)(Vb + (size_t)(ht * 16 + lr) * NT + s0 + lg * 8);
            o[ht] = __builtin_amdgcn_mfma_f32_16x16x32_f16(pf, vf, o[ht], 0, 0, 0);
        }
        __builtin_amdgcn_wave_barrier();
    }

#pragma unroll
    for (int r = 0; r < 4; ++r) {
        int qt = qrow + lg * 4 + r;
        size_t slot = ((size_t)b * NT + qt) * MAXC + c;
#pragma unroll
        for (int ht = 0; ht < 4; ++ht)
            op[slot * NH + ht * 16 + lr] = (f16)o[ht][r];
        if (lr == 0) {
            float2 v; v.x = mrow[r]; v.y = lrow[r];
            ml[slot] = v;
        }
    }
}

// ---------------- kernel 3: combine split-KV partials --------------------
__global__ __launch_bounds__(256) void combine_kernel(
        const f16* __restrict__ op, const float2* __restrict__ ml,
        float* __restrict__ out) {
    int gid = blockIdx.x * 256 + threadIdx.x;
    int row = gid >> 6;
    int h = gid & 63;
    int q = row & (NT - 1);
    int qi = q >> 6;
    int nc = (qi + 4) >> 2;

    size_t base = (size_t)row * MAXC;
    float2 ml0 = ml[base];
    float M = ml0.x, L = ml0.y;
    float O = (float)op[base * NH + h];
    for (int cc = 1; cc < nc; ++cc) {
        float2 mlc = ml[base + cc];
        if (mlc.x == -INFINITY) continue;
        float oc = (float)op[(base + cc) * NH + h];
        float nM = fmaxf(M, mlc.x);
        float wo = __expf(M - nM), wc = __expf(mlc.x - nM);
        O = O * wo + oc * wc;
        L = L * wo + mlc.y * wc;
        M = nM;
    }
    out[gid] = O / L;
}

extern "C" void kernel_launch(void* const* d_in, const int* in_sizes, int n_in,
                              void* d_out, int out_size, void* d_ws, size_t ws_size,
                              hipStream_t stream) {
    const float* x  = (const float*)d_in[0];
    const float* Wk = (const float*)d_in[1];
    const float* Wq = (const float*)d_in[2];
    const float* Wv = (const float*)d_in[3];
    float* out = (float*)d_out;

    char* ws = (char*)d_ws;
    f16* wt    = (f16*)(ws + OFF_WT);
    f16* Qh    = (f16*)(ws + OFF_QH);
    f16* Kh    = (f16*)(ws + OFF_KH);
    f16* VT    = (f16*)(ws + OFF_VT);
    float2* ml = (float2*)(ws + OFF_ML);
    f16* op    = (f16*)(ws + OFF_OP);

    hipLaunchKernelGGL(wconv_kernel, dim3(48), dim3(256), 0, stream, Wk, Wq, Wv, wt);
    hipLaunchKernelGGL(qkv_proj_kernel, dim3(256), dim3(256), 0, stream, x, wt, Qh, Kh, VT);
    hipLaunchKernelGGL(attn_part_kernel, dim3(NB * CHUNKS_PER_BATCH), dim3(256), 0, stream,
                       Qh, Kh, VT, op, ml);
    hipLaunchKernelGGL(combine_kernel, dim3(NB * NT * NH / 256), dim3(256), 0, stream,
                       op, ml, out);
}